// Round 3
// baseline (1779.733 us; speedup 1.0000x reference)
//
#include <hip/hip_runtime.h>
#include <hip/hip_bf16.h>

// Mamba4Rec fused forward. B=1024, L=200, D=64, DI=128, N=32, K=4, R=4, F=256.
constexpr int Bn = 1024, Ln = 200, Dm = 64, DI = 128, Fh = 256;
constexpr int T = 8, NT = 25;          // tokens per tile, tiles (25*8=200)

#define DEVFN __device__ __forceinline__

DEVFN float silu_(float x){ return x / (1.f + __expf(-x)); }
DEVFN float softplus_(float x){ return x > 20.f ? x : log1pf(__expf(x)); }
DEVFN float gelu_tanh_(float x){
  float c = 0.7978845608028654f * (x + 0.044715f * x * x * x);
  float e = __expf(2.f * c);
  float th = 1.f - 2.f / (e + 1.f);
  return 0.5f * x * (1.f + th);
}
DEVFN float wave64_sum(float v){
  #pragma unroll
  for (int off = 32; off; off >>= 1) v += __shfl_xor(v, off, 64);
  return v;
}

// ============ Kernel A: embed+LN+in_proj+conv+x_proj+dt_proj+scan+gate -> y ============
// One block per sequence b; 256 threads; streams 25 tiles of 8 tokens through LDS.
// Only output to HBM: gated y [B,L,DI] (100 MB workspace total).
__global__ __launch_bounds__(256) void kA_fused(
    const int* __restrict__ ids, const float* __restrict__ emb,
    const float* __restrict__ lnw, const float* __restrict__ lnb,
    const float* __restrict__ ipw, const float* __restrict__ cw, const float* __restrict__ cb,
    const float* __restrict__ xpw, const float* __restrict__ dtw, const float* __restrict__ dtb,
    const float* __restrict__ A_log, const float* __restrict__ Dp_g,
    float* __restrict__ y_g)
{
  __shared__ float xls[T][Dm];        // post-LN embeddings          2 KB
  __shared__ float xct[T + 3][DI];    // conv ring: rows 0..2 halo   5.5 KB
  __shared__ float z_s[T][DI];        //                             4 KB
  __shared__ float xs_s[T][132];      // conv+silu out (padded)      4.2 KB
  __shared__ float psum[4][64 * T];   // x_proj K-split partials     8 KB
  __shared__ float bc_s[T][68];       // B(0..31), C(32..63), pad    2.2 KB
  __shared__ float dtlo_s[T][4];
  __shared__ float xpw_ext[4][DI];    // x_proj rows 64..67          2 KB

  const int b = blockIdx.x, tid = threadIdx.x;
  const int wv = tid >> 6, ln = tid & 63;

  // ---- stationary weights ----
  float wip[64];                       // in_proj row tid
  { const float4* p = (const float4*)(ipw + tid * Dm);
    #pragma unroll
    for (int k = 0; k < 16; k++) ((float4*)wip)[k] = p[k]; }
  float wxp[32];                       // x_proj row ln, K-quarter wv
  { const float4* p = (const float4*)(xpw + ln * DI + wv * 32);
    #pragma unroll
    for (int k = 0; k < 8; k++) ((float4*)wxp)[k] = p[k]; }
  const int cd = tid & (DI - 1);       // conv channel
  const float4 cwv = *(const float4*)(cw + cd * 4);
  const float cbv = cb[cd];
  const int sd = tid >> 1, hf = tid & 1;   // scan: channel sd, state-half hf
  const float4 dtwv = *(const float4*)(dtw + sd * 4);
  const float dtbv = dtb[sd], Dpv = Dp_g[sd];
  float A[16];
  { const float4* p = (const float4*)(A_log + sd * 32 + hf * 16);
    #pragma unroll
    for (int k = 0; k < 4; k++) {
      float4 v = p[k];
      A[4*k+0] = -__expf(v.x); A[4*k+1] = -__expf(v.y);
      A[4*k+2] = -__expf(v.z); A[4*k+3] = -__expf(v.w);
    } }
  float h[16];
  #pragma unroll
  for (int k = 0; k < 16; k++) h[k] = 0.f;
  const float lwv = lnw[ln], lbv = lnb[ln];

  for (int i = tid; i < 4 * DI; i += 256) xpw_ext[i >> 7][i & 127] = xpw[64 * DI + i];
  for (int i = tid; i < 3 * DI; i += 256) xct[i >> 7][i & 127] = 0.f;   // t<0 halo
  __syncthreads();

  const int* idb = ids + b * Ln;
  for (int tile = 0; tile < NT; ++tile) {
    const int t0 = tile * T;
    // ---- 1. embed + LN (wave per token, lane = dim) ----
    #pragma unroll
    for (int s = 0; s < 2; s++) {
      int i = wv + 4 * s;
      float v = emb[(long)idb[t0 + i] * Dm + ln];
      float mu  = wave64_sum(v) * (1.f / 64.f);
      float dv  = v - mu;
      float var = wave64_sum(dv * dv) * (1.f / 64.f);
      xls[i][ln] = dv * rsqrtf(var + 1e-12f) * lwv + lbv;
    }
    __syncthreads();
    // ---- 2. in_proj (thread = weight row; LDS broadcast activations) ----
    #pragma unroll
    for (int i = 0; i < T; i++) {
      const float4* xp = (const float4*)xls[i];
      float acc = 0.f;
      #pragma unroll
      for (int k = 0; k < 16; k++) {
        float4 x = xp[k];
        acc += wip[4*k+0]*x.x + wip[4*k+1]*x.y + wip[4*k+2]*x.z + wip[4*k+3]*x.w;
      }
      if (tid < DI) xct[3 + i][tid] = acc;
      else          z_s[i][tid - DI] = acc;
    }
    __syncthreads();
    // ---- 3. depthwise conv(K=4) + SiLU ----
    #pragma unroll
    for (int s = 0; s < 4; s++) {
      int tt = (tid + 256 * s) >> 7;
      float v = cbv + cwv.x * xct[tt + 0][cd] + cwv.y * xct[tt + 1][cd]
                    + cwv.z * xct[tt + 2][cd] + cwv.w * xct[tt + 3][cd];
      xs_s[tt][cd] = silu_(v);
    }
    __syncthreads();
    // ---- 4. x_proj: rows 0..63 K-split by wave; rows 64..67 via LDS weights ----
    #pragma unroll
    for (int t = 0; t < T; t++) {
      const float4* xr = (const float4*)(&xs_s[t][wv * 32]);
      float a = 0.f;
      #pragma unroll
      for (int k = 0; k < 8; k++) {
        float4 x = xr[k];
        a += wxp[4*k+0]*x.x + wxp[4*k+1]*x.y + wxp[4*k+2]*x.z + wxp[4*k+3]*x.w;
      }
      psum[wv][ln * T + t] = a;
    }
    if (tid < 32) {
      int j = tid >> 3, t = tid & 7;
      const float4* wr = (const float4*)xpw_ext[j];
      const float4* xr = (const float4*)(&xs_s[t][0]);
      float a = 0.f;
      #pragma unroll
      for (int k = 0; k < 32; k++) {
        float4 w4 = wr[k]; float4 x = xr[k];
        a += w4.x*x.x + w4.y*x.y + w4.z*x.z + w4.w*x.w;
      }
      bc_s[t][60 + j] = a;     // rows 64..67 -> n = 60..63 (C 28..31)
    }
    __syncthreads();
    // ---- 5. reduce K-split partials -> dt_lo, B, C ----
    #pragma unroll
    for (int s = 0; s < 2; s++) {
      int o = tid + 256 * s;
      int j = o >> 3, t = o & 7;
      float sum = psum[0][o] + psum[1][o] + psum[2][o] + psum[3][o];
      if (j < 4) dtlo_s[t][j] = sum;
      else       bc_s[t][j - 4] = sum;
    }
    __syncthreads();
    // ---- 6. scan (+dt_proj+softplus, +D*xs, *silu(z)) -> y_g; then ring shift ----
    for (int t = 0; t < T; t++) {
      float4 dl = *(const float4*)dtlo_s[t];
      float dtv = softplus_(dtwv.x*dl.x + dtwv.y*dl.y + dtwv.z*dl.z + dtwv.w*dl.w + dtbv);
      float xsv = xs_s[t][sd];
      float zv  = z_s[t][sd];
      float du  = dtv * xsv;
      const float4* bp = (const float4*)(&bc_s[t][hf * 16]);
      const float4* cp = (const float4*)(&bc_s[t][32 + hf * 16]);
      float y = 0.f;
      #pragma unroll
      for (int k = 0; k < 4; k++) {
        float4 Bv = bp[k], Cv = cp[k];
        float h0 = __expf(dtv*A[4*k+0]) * h[4*k+0] + du * Bv.x; h[4*k+0] = h0; y += h0 * Cv.x;
        float h1 = __expf(dtv*A[4*k+1]) * h[4*k+1] + du * Bv.y; h[4*k+1] = h1; y += h1 * Cv.y;
        float h2 = __expf(dtv*A[4*k+2]) * h[4*k+2] + du * Bv.z; h[4*k+2] = h2; y += h2 * Cv.z;
        float h3 = __expf(dtv*A[4*k+3]) * h[4*k+3] + du * Bv.w; h[4*k+3] = h3; y += h3 * Cv.w;
      }
      float yo = y + __shfl_xor(y, 1, 64);
      if (hf == 0)
        y_g[((long)b * Ln + t0 + t) * DI + sd] = (yo + Dpv * xsv) * silu_(zv);
    }
    for (int i = tid; i < 3 * DI; i += 256)   // ring shift: rows 8..10 -> 0..2
      xct[i >> 7][i & 127] = xct[T + (i >> 7)][i & 127];
    __syncthreads();
  }
}

// ============ Kernel B: out_proj + LN + FFN(GELU) + LN -> out ============
__global__ __launch_bounds__(256, 2) void kB_out_ffn(
    const float* __restrict__ y_g, const float* __restrict__ opw,
    const float* __restrict__ mlnw, const float* __restrict__ mlnb,
    const float* __restrict__ w1, const float* __restrict__ b1,
    const float* __restrict__ w2, const float* __restrict__ b2,
    const float* __restrict__ flnw, const float* __restrict__ flnb,
    float* __restrict__ out)
{
  __shared__ float y4[4 * DI];
  __shared__ float psum[4][256];
  __shared__ float hid4[256];
  __shared__ float f4[4 * Fh];
  const int b = blockIdx.x, tid = threadIdx.x;
  const int q = tid >> 6, ln = tid & 63;

  float opreg[32], w1row[64], w2part[64];
  {
    const float4* p = (const float4*)(opw + ln * DI + q * 32);
    #pragma unroll
    for (int k = 0; k < 8; k++) ((float4*)opreg)[k] = p[k];
    const float4* p1 = (const float4*)(w1 + tid * Dm);
    #pragma unroll
    for (int k = 0; k < 16; k++) ((float4*)w1row)[k] = p1[k];
    const float4* p2 = (const float4*)(w2 + ln * Fh + q * 64);
    #pragma unroll
    for (int k = 0; k < 16; k++) ((float4*)w2part)[k] = p2[k];
  }
  const float b1v = b1[tid], b2v = b2[ln];
  const float mw = mlnw[ln], mb = mlnb[ln], fw = flnw[ln], fb = flnb[ln];

  for (int t0 = 0; t0 < Ln; t0 += 4) {
    const long ybase = ((long)b * Ln + t0) * DI;
    for (int i = tid; i < 4 * DI; i += 256) y4[i] = y_g[ybase + i];
    __syncthreads();
    #pragma unroll
    for (int tok = 0; tok < 4; tok++) {
      const float4* yp = (const float4*)(y4 + tok * DI + q * 32);
      float acc = 0.f;
      #pragma unroll
      for (int k = 0; k < 8; k++) {
        float4 yv = yp[k];
        acc += opreg[4*k+0]*yv.x + opreg[4*k+1]*yv.y + opreg[4*k+2]*yv.z + opreg[4*k+3]*yv.w;
      }
      psum[q][tok * 64 + ln] = acc;
    }
    __syncthreads();
    {
      const int tok = q;
      float mout = psum[0][tok*64+ln] + psum[1][tok*64+ln]
                 + psum[2][tok*64+ln] + psum[3][tok*64+ln];
      float mu  = wave64_sum(mout) * (1.f / 64.f);
      float dv  = mout - mu;
      float var = wave64_sum(dv * dv) * (1.f / 64.f);
      hid4[tok * 64 + ln] = dv * rsqrtf(var + 1e-12f) * mw + mb;
    }
    __syncthreads();
    #pragma unroll
    for (int tok = 0; tok < 4; tok++) {
      const float4* hp = (const float4*)(hid4 + tok * 64);
      float a = b1v;
      #pragma unroll
      for (int k = 0; k < 16; k++) {
        float4 hv = hp[k];
        a += w1row[4*k+0]*hv.x + w1row[4*k+1]*hv.y + w1row[4*k+2]*hv.z + w1row[4*k+3]*hv.w;
      }
      f4[tok * Fh + tid] = gelu_tanh_(a);
    }
    __syncthreads();
    #pragma unroll
    for (int tok = 0; tok < 4; tok++) {
      const float4* fp = (const float4*)(f4 + tok * Fh + q * 64);
      float acc = 0.f;
      #pragma unroll
      for (int k = 0; k < 16; k++) {
        float4 fv = fp[k];
        acc += w2part[4*k+0]*fv.x + w2part[4*k+1]*fv.y + w2part[4*k+2]*fv.z + w2part[4*k+3]*fv.w;
      }
      psum[q][tok * 64 + ln] = acc;
    }
    __syncthreads();
    {
      const int tok = q;
      float o = psum[0][tok*64+ln] + psum[1][tok*64+ln]
              + psum[2][tok*64+ln] + psum[3][tok*64+ln] + b2v;
      float res = o + hid4[tok * 64 + ln];
      float mu  = wave64_sum(res) * (1.f / 64.f);
      float dv  = res - mu;
      float var = wave64_sum(dv * dv) * (1.f / 64.f);
      out[((long)b * Ln + t0 + tok) * Dm + ln] = dv * rsqrtf(var + 1e-12f) * fw + fb;
    }
    __syncthreads();
  }
}

extern "C" void kernel_launch(void* const* d_in, const int* in_sizes, int n_in,
                              void* d_out, int out_size, void* d_ws, size_t ws_size,
                              hipStream_t stream)
{
  const int*   ids  = (const int*)  d_in[0];
  const float* emb  = (const float*)d_in[1];
  const float* lnw  = (const float*)d_in[2];
  const float* lnb  = (const float*)d_in[3];
  const float* ipw  = (const float*)d_in[4];
  const float* cw   = (const float*)d_in[5];
  const float* cb   = (const float*)d_in[6];
  const float* xpw  = (const float*)d_in[7];
  const float* dtw  = (const float*)d_in[8];
  const float* dtb  = (const float*)d_in[9];
  const float* alog = (const float*)d_in[10];
  const float* Dp   = (const float*)d_in[11];
  const float* opw  = (const float*)d_in[12];
  const float* mlnw = (const float*)d_in[13];
  const float* mlnb = (const float*)d_in[14];
  const float* w1   = (const float*)d_in[15];
  const float* b1   = (const float*)d_in[16];
  const float* w2   = (const float*)d_in[17];
  const float* b2   = (const float*)d_in[18];
  const float* flnw = (const float*)d_in[19];
  const float* flnb = (const float*)d_in[20];
  float* out = (float*)d_out;

  float* y = (float*)d_ws;   // [B,L,DI] = 104,857,600 B — the ONLY workspace use

  kA_fused<<<Bn, 256, 0, stream>>>(ids, emb, lnw, lnb, ipw, cw, cb, xpw,
                                   dtw, dtb, alog, Dp, y);
  kB_out_ffn<<<Bn, 256, 0, stream>>>(y, opw, mlnw, mlnb, w1, b1, w2, b2,
                                     flnw, flnb, out);
}

// Round 4
// 1379.379 us; speedup vs baseline: 1.2902x; 1.2902x over previous
//
#include <hip/hip_runtime.h>
#include <hip/hip_bf16.h>

// Mamba4Rec fused forward. B=1024, L=200, D=64, DI=128, N=32, K=4, R=4, F=256.
constexpr int Bn = 1024, Ln = 200, Dm = 64, DI = 128, Fh = 256;

#define DEVFN __device__ __forceinline__

DEVFN float silu_(float x){ return x / (1.f + __expf(-x)); }
DEVFN float softplus_(float x){ return x > 20.f ? x : log1pf(__expf(x)); }
DEVFN float gelu_tanh_(float x){
  float c = 0.7978845608028654f * (x + 0.044715f * x * x * x);
  float e = __expf(2.f * c);
  float th = 1.f - 2.f / (e + 1.f);
  return 0.5f * x * (1.f + th);
}
DEVFN float wave64_sum(float v){
  #pragma unroll
  for (int off = 32; off; off >>= 1) v += __shfl_xor(v, off, 64);
  return v;
}
DEVFN unsigned short f2b(float f){           // f32 -> bf16 RNE
  unsigned int u = __float_as_uint(f);
  return (unsigned short)((u + 0x7fffu + ((u >> 16) & 1u)) >> 16);
}
DEVFN float b2f(unsigned short h){ return __uint_as_float(((unsigned int)h) << 16); }

// ============ K1: embed + LN + in_proj -> xc (bf16), z (bf16) ============
// grid 1024*5, 256 threads; thread = in_proj output row (64 stationary VGPRs).
__global__ __launch_bounds__(256, 4) void k1_embed_inproj(
    const int* __restrict__ ids, const float* __restrict__ emb,
    const float* __restrict__ lnw, const float* __restrict__ lnb,
    const float* __restrict__ ipw,
    unsigned short* __restrict__ xc, unsigned short* __restrict__ zy)
{
  __shared__ float xls[8][Dm];
  const int blk = blockIdx.x, b = blk / 5, t0 = (blk % 5) * 40;
  const int tid = threadIdx.x, wv = tid >> 6, ln = tid & 63;
  float wip[64];
  { const float4* p = (const float4*)(ipw + tid * Dm);
    #pragma unroll
    for (int k = 0; k < 16; k++) ((float4*)wip)[k] = p[k]; }
  const float lw = lnw[ln], lb = lnb[ln];
  const int* idb = ids + b * Ln;

  for (int sub = 0; sub < 5; sub++) {
    const int tt0 = t0 + sub * 8;
    #pragma unroll
    for (int s = 0; s < 2; s++) {
      int i = wv + 4 * s;
      float v = emb[(long)idb[tt0 + i] * Dm + ln];
      float mu  = wave64_sum(v) * (1.f / 64.f);
      float dv  = v - mu;
      float var = wave64_sum(dv * dv) * (1.f / 64.f);
      xls[i][ln] = dv * rsqrtf(var + 1e-12f) * lw + lb;
    }
    __syncthreads();
    #pragma unroll
    for (int i = 0; i < 8; i++) {
      const float4* xp = (const float4*)xls[i];
      float acc = 0.f;
      #pragma unroll
      for (int k = 0; k < 16; k++) {
        float4 x = xp[k];
        acc += wip[4*k+0]*x.x + wip[4*k+1]*x.y + wip[4*k+2]*x.z + wip[4*k+3]*x.w;
      }
      long idx = ((long)b * Ln + tt0 + i) * DI;
      unsigned short hv = f2b(acc);
      if (tid < DI) xc[idx + tid] = hv;
      else          zy[idx + tid - DI] = hv;
    }
    __syncthreads();
  }
}

// ============ K2: conv + SiLU + x_proj + dt_proj + scan + gate -> y (bf16, over z) ============
// grid 1024 (one block per sequence), 256 threads, ~27.5 KB LDS, fully resident.
__global__ __launch_bounds__(256, 4) void k2_conv_scan(
    const unsigned short* __restrict__ xc, unsigned short* __restrict__ zy,
    const float* __restrict__ cw, const float* __restrict__ cb,
    const float* __restrict__ xpw, const float* __restrict__ dtw, const float* __restrict__ dtb,
    const float* __restrict__ A_log, const float* __restrict__ Dp_g)
{
  constexpr int T = 8;
  __shared__ float xct[T + 3][DI];        // conv ring, rows 0..2 halo
  __shared__ float xs_s[T][132];
  __shared__ unsigned short z_s[T][DI];
  __shared__ unsigned short y_s[T][DI];
  __shared__ float psum[4][64 * 9];       // pitch 9: gcd(9,32)=1, conflict-free
  __shared__ float bc_s[T][68];
  __shared__ float dtlo_s[T][4];
  __shared__ float xpw_ext[4][DI];

  const int b = blockIdx.x, tid = threadIdx.x;
  const int wv = tid >> 6, ln = tid & 63;

  float wxp[32];
  { const float4* p = (const float4*)(xpw + ln * DI + wv * 32);
    #pragma unroll
    for (int k = 0; k < 8; k++) ((float4*)wxp)[k] = p[k]; }
  const int cd = tid & (DI - 1);
  const float4 cwv = *(const float4*)(cw + cd * 4);
  const float cbv = cb[cd];
  const int sd = tid >> 1, hf = tid & 1;
  const float4 dtwv = *(const float4*)(dtw + sd * 4);
  const float dtbv = dtb[sd], Dpv = Dp_g[sd];
  float A[16];
  { const float4* p = (const float4*)(A_log + sd * 32 + hf * 16);
    #pragma unroll
    for (int k = 0; k < 4; k++) {
      float4 v = p[k];
      A[4*k+0] = -__expf(v.x); A[4*k+1] = -__expf(v.y);
      A[4*k+2] = -__expf(v.z); A[4*k+3] = -__expf(v.w);
    } }
  float h[16];
  #pragma unroll
  for (int k = 0; k < 16; k++) h[k] = 0.f;

  for (int i = tid; i < 4 * DI; i += 256) xpw_ext[i >> 7][i & 127] = xpw[64 * DI + i];
  for (int i = tid; i < 3 * DI; i += 256) xct[i >> 7][i & 127] = 0.f;
  __syncthreads();

  for (int tile = 0; tile < 25; ++tile) {
    const int t0 = tile * T;
    const long gbase = ((long)b * Ln + t0) * DI;
    // ---- stage xc (cvt->f32 ring) and z (raw bf16) ----
    {
      ushort4 xv = ((const ushort4*)(xc + gbase))[tid];
      ushort4 zv = ((const ushort4*)(zy + gbase))[tid];
      int row = tid >> 5, col = (tid & 31) * 4;
      xct[3 + row][col + 0] = b2f(xv.x); xct[3 + row][col + 1] = b2f(xv.y);
      xct[3 + row][col + 2] = b2f(xv.z); xct[3 + row][col + 3] = b2f(xv.w);
      ((ushort4*)z_s)[tid] = zv;
    }
    __syncthreads();
    // ---- conv + SiLU ----
    #pragma unroll
    for (int s = 0; s < 4; s++) {
      int tt = (tid >> 7) + 2 * s;
      float v = cbv + cwv.x * xct[tt + 0][cd] + cwv.y * xct[tt + 1][cd]
                    + cwv.z * xct[tt + 2][cd] + cwv.w * xct[tt + 3][cd];
      xs_s[tt][cd] = silu_(v);
    }
    __syncthreads();
    // ---- x_proj: rows 0..63 K-split by wave; rows 64..67 full-K by 32 threads ----
    #pragma unroll
    for (int t = 0; t < T; t++) {
      const float4* xr = (const float4*)(&xs_s[t][wv * 32]);
      float a = 0.f;
      #pragma unroll
      for (int k = 0; k < 8; k++) {
        float4 x = xr[k];
        a += wxp[4*k+0]*x.x + wxp[4*k+1]*x.y + wxp[4*k+2]*x.z + wxp[4*k+3]*x.w;
      }
      psum[wv][ln * 9 + t] = a;
    }
    if (tid < 32) {
      int j = tid >> 3, t = tid & 7;
      const float4* wr = (const float4*)xpw_ext[j];
      const float4* xr = (const float4*)(&xs_s[t][0]);
      float a = 0.f;
      #pragma unroll
      for (int k = 0; k < 32; k++) {
        float4 w4 = wr[k]; float4 x = xr[k];
        a += w4.x*x.x + w4.y*x.y + w4.z*x.z + w4.w*x.w;
      }
      bc_s[t][60 + j] = a;
    }
    __syncthreads();
    // ---- reduce K-split partials ----
    #pragma unroll
    for (int s = 0; s < 2; s++) {
      int o = tid + 256 * s;
      int j = o >> 3, t = o & 7;
      float sum = psum[0][j*9+t] + psum[1][j*9+t] + psum[2][j*9+t] + psum[3][j*9+t];
      if (j < 4) dtlo_s[t][j] = sum;
      else       bc_s[t][j - 4] = sum;
    }
    __syncthreads();
    // ---- scan ----
    for (int t = 0; t < T; t++) {
      float4 dl = *(const float4*)dtlo_s[t];
      float dtv = softplus_(dtwv.x*dl.x + dtwv.y*dl.y + dtwv.z*dl.z + dtwv.w*dl.w + dtbv);
      float xsv = xs_s[t][sd];
      float zv  = b2f(z_s[t][sd]);
      float du  = dtv * xsv;
      const float4* bp = (const float4*)(&bc_s[t][hf * 16]);
      const float4* cp = (const float4*)(&bc_s[t][32 + hf * 16]);
      float y = 0.f;
      #pragma unroll
      for (int k = 0; k < 4; k++) {
        float4 Bv = bp[k], Cv = cp[k];
        float h0 = __expf(dtv*A[4*k+0]) * h[4*k+0] + du * Bv.x; h[4*k+0] = h0; y += h0 * Cv.x;
        float h1 = __expf(dtv*A[4*k+1]) * h[4*k+1] + du * Bv.y; h[4*k+1] = h1; y += h1 * Cv.y;
        float h2 = __expf(dtv*A[4*k+2]) * h[4*k+2] + du * Bv.z; h[4*k+2] = h2; y += h2 * Cv.z;
        float h3 = __expf(dtv*A[4*k+3]) * h[4*k+3] + du * Bv.w; h[4*k+3] = h3; y += h3 * Cv.w;
      }
      float yo = y + __shfl_xor(y, 1, 64);
      if (hf == 0)
        y_s[t][sd] = f2b((yo + Dpv * xsv) * silu_(zv));
    }
    __syncthreads();
    // ---- dump y over z; ring shift ----
    ((ushort4*)(zy + gbase))[tid] = ((ushort4*)y_s)[tid];
    for (int i = tid; i < 3 * DI; i += 256)
      xct[i >> 7][i & 127] = xct[8 + (i >> 7)][i & 127];
    __syncthreads();
  }
}

// ============ K3: out_proj + LN + FFN(GELU) + LN -> out ============
// grid 1024, 512 threads; stationary 80 VGPR/thread; 8 tokens per iter.
__global__ __launch_bounds__(512, 4) void k3_out_ffn(
    const unsigned short* __restrict__ y_g, const float* __restrict__ opw,
    const float* __restrict__ mlnw, const float* __restrict__ mlnb,
    const float* __restrict__ w1, const float* __restrict__ b1,
    const float* __restrict__ w2, const float* __restrict__ b2,
    const float* __restrict__ flnw, const float* __restrict__ flnb,
    float* __restrict__ out)
{
  __shared__ float y8[8][DI];          // 4 KB
  __shared__ float psum[4096];         // 16 KB (union: op / ffn1 / ffn2)
  __shared__ float hid8[8][Dm];        // 2 KB
  __shared__ float f4s[8 * Fh];        // 8 KB
  __shared__ float b1_s[Fh];           // 1 KB
  const int b = blockIdx.x, tid = threadIdx.x;
  const int u = tid >> 6, ln = tid & 63;   // 8 waves

  float opp[16], w1h[32], w2p[32];
  { const float4* p = (const float4*)(opw + ln * DI + u * 16);
    #pragma unroll
    for (int k = 0; k < 4; k++) ((float4*)opp)[k] = p[k];
    const float4* p1 = (const float4*)(w1 + (ln + (u & 3) * 64) * Dm + (u >> 2) * 32);
    #pragma unroll
    for (int k = 0; k < 8; k++) ((float4*)w1h)[k] = p1[k];
    const float4* p2 = (const float4*)(w2 + ln * Fh + u * 32);
    #pragma unroll
    for (int k = 0; k < 8; k++) ((float4*)w2p)[k] = p2[k]; }
  for (int i = tid; i < Fh; i += 512) b1_s[i] = b1[i];
  const float b2v = b2[ln];
  const float mw = mlnw[ln], mb = mlnb[ln], fw = flnw[ln], fb = flnb[ln];
  const int h2 = u >> 2, rrow = ln + (u & 3) * 64;

  for (int it = 0; it < 25; ++it) {
    const int t0 = it * 8;
    {
      ushort4 yv = ((const ushort4*)(y_g + ((long)b * Ln + t0) * DI))[tid];
      int row = tid >> 5, col = (tid & 31) * 4;
      y8[row][col + 0] = b2f(yv.x); y8[row][col + 1] = b2f(yv.y);
      y8[row][col + 2] = b2f(yv.z); y8[row][col + 3] = b2f(yv.w);
    }
    __syncthreads();
    // ---- out_proj (K-split 8x16) ----
    #pragma unroll
    for (int t = 0; t < 8; t++) {
      const float4* yp = (const float4*)(&y8[t][u * 16]);
      float acc = 0.f;
      #pragma unroll
      for (int k = 0; k < 4; k++) {
        float4 y = yp[k];
        acc += opp[4*k+0]*y.x + opp[4*k+1]*y.y + opp[4*k+2]*y.z + opp[4*k+3]*y.w;
      }
      psum[u * 512 + t * 64 + ln] = acc;
    }
    __syncthreads();
    {   // wave u owns token u: reduce + LN
      float m = 0.f;
      #pragma unroll
      for (int v = 0; v < 8; v++) m += psum[v * 512 + u * 64 + ln];
      float mu  = wave64_sum(m) * (1.f / 64.f);
      float dv  = m - mu;
      float var = wave64_sum(dv * dv) * (1.f / 64.f);
      hid8[u][ln] = dv * rsqrtf(var + 1e-12f) * mw + mb;
    }
    __syncthreads();
    // ---- ffn1 (K-halves of 32) ----
    #pragma unroll
    for (int t = 0; t < 8; t++) {
      const float4* hp = (const float4*)(&hid8[t][h2 * 32]);
      float acc = 0.f;
      #pragma unroll
      for (int k = 0; k < 8; k++) {
        float4 hv = hp[k];
        acc += w1h[4*k+0]*hv.x + w1h[4*k+1]*hv.y + w1h[4*k+2]*hv.z + w1h[4*k+3]*hv.w;
      }
      psum[h2 * 2048 + t * 256 + rrow] = acc;
    }
    __syncthreads();
    #pragma unroll
    for (int s = 0; s < 4; s++) {
      int o = tid + 512 * s;
      int t = o >> 8, r = o & 255;
      float v = b1_s[r] + psum[t * 256 + r] + psum[2048 + t * 256 + r];
      f4s[t * 256 + r] = gelu_tanh_(v);
    }
    __syncthreads();
    // ---- ffn2 (K-split 8x32) ----
    #pragma unroll
    for (int t = 0; t < 8; t++) {
      const float4* fp = (const float4*)(&f4s[t * 256 + u * 32]);
      float acc = 0.f;
      #pragma unroll
      for (int k = 0; k < 8; k++) {
        float4 fv = fp[k];
        acc += w2p[4*k+0]*fv.x + w2p[4*k+1]*fv.y + w2p[4*k+2]*fv.z + w2p[4*k+3]*fv.w;
      }
      psum[u * 512 + t * 64 + ln] = acc;
    }
    __syncthreads();
    {   // wave u owns token u: reduce + residual + LN + store
      float o2 = b2v;
      #pragma unroll
      for (int v = 0; v < 8; v++) o2 += psum[v * 512 + u * 64 + ln];
      float res = o2 + hid8[u][ln];
      float mu  = wave64_sum(res) * (1.f / 64.f);
      float dv  = res - mu;
      float var = wave64_sum(dv * dv) * (1.f / 64.f);
      out[((long)b * Ln + t0 + u) * Dm + ln] = dv * rsqrtf(var + 1e-12f) * fw + fb;
    }
    __syncthreads();
  }
}

extern "C" void kernel_launch(void* const* d_in, const int* in_sizes, int n_in,
                              void* d_out, int out_size, void* d_ws, size_t ws_size,
                              hipStream_t stream)
{
  const int*   ids  = (const int*)  d_in[0];
  const float* emb  = (const float*)d_in[1];
  const float* lnw  = (const float*)d_in[2];
  const float* lnb  = (const float*)d_in[3];
  const float* ipw  = (const float*)d_in[4];
  const float* cw   = (const float*)d_in[5];
  const float* cb   = (const float*)d_in[6];
  const float* xpw  = (const float*)d_in[7];
  const float* dtw  = (const float*)d_in[8];
  const float* dtb  = (const float*)d_in[9];
  const float* alog = (const float*)d_in[10];
  const float* Dp   = (const float*)d_in[11];
  const float* opw  = (const float*)d_in[12];
  const float* mlnw = (const float*)d_in[13];
  const float* mlnb = (const float*)d_in[14];
  const float* w1   = (const float*)d_in[15];
  const float* b1   = (const float*)d_in[16];
  const float* w2   = (const float*)d_in[17];
  const float* b2   = (const float*)d_in[18];
  const float* flnw = (const float*)d_in[19];
  const float* flnb = (const float*)d_in[20];
  float* out = (float*)d_out;

  const size_t half = (size_t)Bn * Ln * DI * sizeof(unsigned short);  // 52,428,800 B
  unsigned short* xc = (unsigned short*)d_ws;                         // [B,L,DI] bf16
  unsigned short* zy = (unsigned short*)((char*)d_ws + half);         // z, then y in-place

  k1_embed_inproj<<<Bn * 5, 256, 0, stream>>>(ids, emb, lnw, lnb, ipw, xc, zy);
  k2_conv_scan<<<Bn, 256, 0, stream>>>(xc, zy, cw, cb, xpw, dtw, dtb, alog, Dp);
  k3_out_ffn<<<Bn, 512, 0, stream>>>(zy, opw, mlnw, mlnb, w1, b1, w2, b2,
                                     flnw, flnb, out);
}

// Round 8
// 1376.735 us; speedup vs baseline: 1.2927x; 1.0019x over previous
//
#include <hip/hip_runtime.h>
#include <hip/hip_bf16.h>

// Mamba4Rec fused forward. B=1024, L=200, D=64, DI=128, N=32, K=4, R=4, F=256.
constexpr int Bn = 1024, Ln = 200, Dm = 64, DI = 128, Fh = 256;

#define DEVFN __device__ __forceinline__

DEVFN float silu_(float x){ return x / (1.f + __expf(-x)); }
DEVFN float softplus_(float x){ return x > 20.f ? x : log1pf(__expf(x)); }
DEVFN float gelu_tanh_(float x){
  float c = 0.7978845608028654f * (x + 0.044715f * x * x * x);
  float e = __expf(2.f * c);
  float th = 1.f - 2.f / (e + 1.f);
  return 0.5f * x * (1.f + th);
}
DEVFN float wave64_sum(float v){
  #pragma unroll
  for (int off = 32; off; off >>= 1) v += __shfl_xor(v, off, 64);
  return v;
}
DEVFN unsigned short f2b(float f){           // f32 -> bf16 RNE
  unsigned int u = __float_as_uint(f);
  return (unsigned short)((u + 0x7fffu + ((u >> 16) & 1u)) >> 16);
}
DEVFN float b2f(unsigned short h){ return __uint_as_float(((unsigned int)h) << 16); }

// ============ K1: embed + LN + in_proj -> xc (bf16), z (bf16) ============
// grid 1024*5, 256 threads; thread = in_proj output row (64 stationary VGPRs).
// waves_per_eu(4,4): pin VGPR budget at 128 so wip[] stays resident (no spills).
__global__ __attribute__((amdgpu_waves_per_eu(4, 4))) __launch_bounds__(256)
void k1_embed_inproj(
    const int* __restrict__ ids, const float* __restrict__ emb,
    const float* __restrict__ lnw, const float* __restrict__ lnb,
    const float* __restrict__ ipw,
    unsigned short* __restrict__ xc, unsigned short* __restrict__ zy)
{
  __shared__ float xls[8][Dm];
  const int blk = blockIdx.x, b = blk / 5, t0 = (blk % 5) * 40;
  const int tid = threadIdx.x, wv = tid >> 6, ln = tid & 63;
  float wip[64];
  { const float4* p = (const float4*)(ipw + tid * Dm);
    #pragma unroll
    for (int k = 0; k < 16; k++) ((float4*)wip)[k] = p[k]; }
  const float lw = lnw[ln], lb = lnb[ln];
  const int* idb = ids + b * Ln;

  for (int sub = 0; sub < 5; sub++) {
    const int tt0 = t0 + sub * 8;
    #pragma unroll
    for (int s = 0; s < 2; s++) {
      int i = wv + 4 * s;
      float v = emb[(long)idb[tt0 + i] * Dm + ln];
      float mu  = wave64_sum(v) * (1.f / 64.f);
      float dv  = v - mu;
      float var = wave64_sum(dv * dv) * (1.f / 64.f);
      xls[i][ln] = dv * rsqrtf(var + 1e-12f) * lw + lb;
    }
    __syncthreads();
    #pragma unroll
    for (int i = 0; i < 8; i++) {
      const float4* xp = (const float4*)xls[i];
      float acc = 0.f;
      #pragma unroll
      for (int k = 0; k < 16; k++) {
        float4 x = xp[k];
        acc += wip[4*k+0]*x.x + wip[4*k+1]*x.y + wip[4*k+2]*x.z + wip[4*k+3]*x.w;
      }
      long idx = ((long)b * Ln + tt0 + i) * DI;
      unsigned short hv = f2b(acc);
      if (tid < DI) xc[idx + tid] = hv;
      else          zy[idx + tid - DI] = hv;
    }
    __syncthreads();
  }
}

// ============ K2: conv + SiLU + x_proj + dt_proj + scan + gate -> y (bf16, over z) ============
// grid 1024 (one block per sequence), 256 threads, ~27.5 KB LDS.
// waves_per_eu(4,4): grid is 4 blocks/CU anyway; keep wxp/A/h in registers.
__global__ __attribute__((amdgpu_waves_per_eu(4, 4))) __launch_bounds__(256)
void k2_conv_scan(
    const unsigned short* __restrict__ xc, unsigned short* __restrict__ zy,
    const float* __restrict__ cw, const float* __restrict__ cb,
    const float* __restrict__ xpw, const float* __restrict__ dtw, const float* __restrict__ dtb,
    const float* __restrict__ A_log, const float* __restrict__ Dp_g)
{
  constexpr int T = 8;
  __shared__ float xct[T + 3][DI];        // conv ring, rows 0..2 halo
  __shared__ float xs_s[T][132];
  __shared__ unsigned short z_s[T][DI];
  __shared__ unsigned short y_s[T][DI];
  __shared__ float psum[4][64 * 9];       // pitch 9: gcd(9,32)=1, conflict-free
  __shared__ float bc_s[T][68];
  __shared__ float dtlo_s[T][4];
  __shared__ float xpw_ext[4][DI];

  const int b = blockIdx.x, tid = threadIdx.x;
  const int wv = tid >> 6, ln = tid & 63;

  float wxp[32];
  { const float4* p = (const float4*)(xpw + ln * DI + wv * 32);
    #pragma unroll
    for (int k = 0; k < 8; k++) ((float4*)wxp)[k] = p[k]; }
  const int cd = tid & (DI - 1);
  const float4 cwv = *(const float4*)(cw + cd * 4);
  const float cbv = cb[cd];
  const int sd = tid >> 1, hf = tid & 1;
  const float4 dtwv = *(const float4*)(dtw + sd * 4);
  const float dtbv = dtb[sd], Dpv = Dp_g[sd];
  float A[16];
  { const float4* p = (const float4*)(A_log + sd * 32 + hf * 16);
    #pragma unroll
    for (int k = 0; k < 4; k++) {
      float4 v = p[k];
      A[4*k+0] = -__expf(v.x); A[4*k+1] = -__expf(v.y);
      A[4*k+2] = -__expf(v.z); A[4*k+3] = -__expf(v.w);
    } }
  float h[16];
  #pragma unroll
  for (int k = 0; k < 16; k++) h[k] = 0.f;

  for (int i = tid; i < 4 * DI; i += 256) xpw_ext[i >> 7][i & 127] = xpw[64 * DI + i];
  for (int i = tid; i < 3 * DI; i += 256) xct[i >> 7][i & 127] = 0.f;
  __syncthreads();

  for (int tile = 0; tile < 25; ++tile) {
    const int t0 = tile * T;
    const long gbase = ((long)b * Ln + t0) * DI;
    // ---- stage xc (cvt->f32 ring) and z (raw bf16) ----
    {
      ushort4 xv = ((const ushort4*)(xc + gbase))[tid];
      ushort4 zv = ((const ushort4*)(zy + gbase))[tid];
      int row = tid >> 5, col = (tid & 31) * 4;
      xct[3 + row][col + 0] = b2f(xv.x); xct[3 + row][col + 1] = b2f(xv.y);
      xct[3 + row][col + 2] = b2f(xv.z); xct[3 + row][col + 3] = b2f(xv.w);
      ((ushort4*)z_s)[tid] = zv;
    }
    __syncthreads();
    // ---- conv + SiLU ----
    #pragma unroll
    for (int s = 0; s < 4; s++) {
      int tt = (tid >> 7) + 2 * s;
      float v = cbv + cwv.x * xct[tt + 0][cd] + cwv.y * xct[tt + 1][cd]
                    + cwv.z * xct[tt + 2][cd] + cwv.w * xct[tt + 3][cd];
      xs_s[tt][cd] = silu_(v);
    }
    __syncthreads();
    // ---- x_proj: rows 0..63 K-split by wave; rows 64..67 full-K by 32 threads ----
    #pragma unroll
    for (int t = 0; t < T; t++) {
      const float4* xr = (const float4*)(&xs_s[t][wv * 32]);
      float a = 0.f;
      #pragma unroll
      for (int k = 0; k < 8; k++) {
        float4 x = xr[k];
        a += wxp[4*k+0]*x.x + wxp[4*k+1]*x.y + wxp[4*k+2]*x.z + wxp[4*k+3]*x.w;
      }
      psum[wv][ln * 9 + t] = a;
    }
    if (tid < 32) {
      int j = tid >> 3, t = tid & 7;
      const float4* wr = (const float4*)xpw_ext[j];
      const float4* xr = (const float4*)(&xs_s[t][0]);
      float a = 0.f;
      #pragma unroll
      for (int k = 0; k < 32; k++) {
        float4 w4 = wr[k]; float4 x = xr[k];
        a += w4.x*x.x + w4.y*x.y + w4.z*x.z + w4.w*x.w;
      }
      bc_s[t][60 + j] = a;
    }
    __syncthreads();
    // ---- reduce K-split partials ----
    #pragma unroll
    for (int s = 0; s < 2; s++) {
      int o = tid + 256 * s;
      int j = o >> 3, t = o & 7;
      float sum = psum[0][j*9+t] + psum[1][j*9+t] + psum[2][j*9+t] + psum[3][j*9+t];
      if (j < 4) dtlo_s[t][j] = sum;
      else       bc_s[t][j - 4] = sum;
    }
    __syncthreads();
    // ---- scan ----
    for (int t = 0; t < T; t++) {
      float4 dl = *(const float4*)dtlo_s[t];
      float dtv = softplus_(dtwv.x*dl.x + dtwv.y*dl.y + dtwv.z*dl.z + dtwv.w*dl.w + dtbv);
      float xsv = xs_s[t][sd];
      float zv  = b2f(z_s[t][sd]);
      float du  = dtv * xsv;
      const float4* bp = (const float4*)(&bc_s[t][hf * 16]);
      const float4* cp = (const float4*)(&bc_s[t][32 + hf * 16]);
      float y = 0.f;
      #pragma unroll
      for (int k = 0; k < 4; k++) {
        float4 Bv = bp[k], Cv = cp[k];
        float h0 = __expf(dtv*A[4*k+0]) * h[4*k+0] + du * Bv.x; h[4*k+0] = h0; y += h0 * Cv.x;
        float h1 = __expf(dtv*A[4*k+1]) * h[4*k+1] + du * Bv.y; h[4*k+1] = h1; y += h1 * Cv.y;
        float h2 = __expf(dtv*A[4*k+2]) * h[4*k+2] + du * Bv.z; h[4*k+2] = h2; y += h2 * Cv.z;
        float h3 = __expf(dtv*A[4*k+3]) * h[4*k+3] + du * Bv.w; h[4*k+3] = h3; y += h3 * Cv.w;
      }
      float yo = y + __shfl_xor(y, 1, 64);
      if (hf == 0)
        y_s[t][sd] = f2b((yo + Dpv * xsv) * silu_(zv));
    }
    __syncthreads();
    // ---- dump y over z; ring shift ----
    ((ushort4*)(zy + gbase))[tid] = ((ushort4*)y_s)[tid];
    for (int i = tid; i < 3 * DI; i += 256)
      xct[i >> 7][i & 127] = xct[8 + (i >> 7)][i & 127];
    __syncthreads();
  }
}

// ============ K3: out_proj + LN + FFN(GELU) + LN -> out ============
// grid 1024, 512 threads; stationary 80 VGPR/thread; 8 tokens per iter.
// waves_per_eu(4,4): 2 blocks/CU target; VGPR budget 128, no spill squeeze.
__global__ __attribute__((amdgpu_waves_per_eu(4, 4))) __launch_bounds__(512)
void k3_out_ffn(
    const unsigned short* __restrict__ y_g, const float* __restrict__ opw,
    const float* __restrict__ mlnw, const float* __restrict__ mlnb,
    const float* __restrict__ w1, const float* __restrict__ b1,
    const float* __restrict__ w2, const float* __restrict__ b2,
    const float* __restrict__ flnw, const float* __restrict__ flnb,
    float* __restrict__ out)
{
  __shared__ float y8[8][DI];          // 4 KB
  __shared__ float psum[4096];         // 16 KB (union: op / ffn1 / ffn2)
  __shared__ float hid8[8][Dm];        // 2 KB
  __shared__ float f4s[8 * Fh];        // 8 KB
  __shared__ float b1_s[Fh];           // 1 KB
  const int b = blockIdx.x, tid = threadIdx.x;
  const int u = tid >> 6, ln = tid & 63;   // 8 waves

  float opp[16], w1h[32], w2p[32];
  { const float4* p = (const float4*)(opw + ln * DI + u * 16);
    #pragma unroll
    for (int k = 0; k < 4; k++) ((float4*)opp)[k] = p[k];
    const float4* p1 = (const float4*)(w1 + (ln + (u & 3) * 64) * Dm + (u >> 2) * 32);
    #pragma unroll
    for (int k = 0; k < 8; k++) ((float4*)w1h)[k] = p1[k];
    const float4* p2 = (const float4*)(w2 + ln * Fh + u * 32);
    #pragma unroll
    for (int k = 0; k < 8; k++) ((float4*)w2p)[k] = p2[k]; }
  for (int i = tid; i < Fh; i += 512) b1_s[i] = b1[i];
  const float b2v = b2[ln];
  const float mw = mlnw[ln], mb = mlnb[ln], fw = flnw[ln], fb = flnb[ln];
  const int h2 = u >> 2, rrow = ln + (u & 3) * 64;

  for (int it = 0; it < 25; ++it) {
    const int t0 = it * 8;
    {
      ushort4 yv = ((const ushort4*)(y_g + ((long)b * Ln + t0) * DI))[tid];
      int row = tid >> 5, col = (tid & 31) * 4;
      y8[row][col + 0] = b2f(yv.x); y8[row][col + 1] = b2f(yv.y);
      y8[row][col + 2] = b2f(yv.z); y8[row][col + 3] = b2f(yv.w);
    }
    __syncthreads();
    // ---- out_proj (K-split 8x16) ----
    #pragma unroll
    for (int t = 0; t < 8; t++) {
      const float4* yp = (const float4*)(&y8[t][u * 16]);
      float acc = 0.f;
      #pragma unroll
      for (int k = 0; k < 4; k++) {
        float4 y = yp[k];
        acc += opp[4*k+0]*y.x + opp[4*k+1]*y.y + opp[4*k+2]*y.z + opp[4*k+3]*y.w;
      }
      psum[u * 512 + t * 64 + ln] = acc;
    }
    __syncthreads();
    {   // wave u owns token u: reduce + LN
      float m = 0.f;
      #pragma unroll
      for (int v = 0; v < 8; v++) m += psum[v * 512 + u * 64 + ln];
      float mu  = wave64_sum(m) * (1.f / 64.f);
      float dv  = m - mu;
      float var = wave64_sum(dv * dv) * (1.f / 64.f);
      hid8[u][ln] = dv * rsqrtf(var + 1e-12f) * mw + mb;
    }
    __syncthreads();
    // ---- ffn1 (K-halves of 32) ----
    #pragma unroll
    for (int t = 0; t < 8; t++) {
      const float4* hp = (const float4*)(&hid8[t][h2 * 32]);
      float acc = 0.f;
      #pragma unroll
      for (int k = 0; k < 8; k++) {
        float4 hv = hp[k];
        acc += w1h[4*k+0]*hv.x + w1h[4*k+1]*hv.y + w1h[4*k+2]*hv.z + w1h[4*k+3]*hv.w;
      }
      psum[h2 * 2048 + t * 256 + rrow] = acc;
    }
    __syncthreads();
    #pragma unroll
    for (int s = 0; s < 4; s++) {
      int o = tid + 512 * s;
      int t = o >> 8, r = o & 255;
      float v = b1_s[r] + psum[t * 256 + r] + psum[2048 + t * 256 + r];
      f4s[t * 256 + r] = gelu_tanh_(v);
    }
    __syncthreads();
    // ---- ffn2 (K-split 8x32) ----
    #pragma unroll
    for (int t = 0; t < 8; t++) {
      const float4* fp = (const float4*)(&f4s[t * 256 + u * 32]);
      float acc = 0.f;
      #pragma unroll
      for (int k = 0; k < 8; k++) {
        float4 fv = fp[k];
        acc += w2p[4*k+0]*fv.x + w2p[4*k+1]*fv.y + w2p[4*k+2]*fv.z + w2p[4*k+3]*fv.w;
      }
      psum[u * 512 + t * 64 + ln] = acc;
    }
    __syncthreads();
    {   // wave u owns token u: reduce + residual + LN + store
      float o2 = b2v;
      #pragma unroll
      for (int v = 0; v < 8; v++) o2 += psum[v * 512 + u * 64 + ln];
      float res = o2 + hid8[u][ln];
      float mu  = wave64_sum(res) * (1.f / 64.f);
      float dv  = res - mu;
      float var = wave64_sum(dv * dv) * (1.f / 64.f);
      out[((long)b * Ln + t0 + u) * Dm + ln] = dv * rsqrtf(var + 1e-12f) * fw + fb;
    }
    __syncthreads();
  }
}

extern "C" void kernel_launch(void* const* d_in, const int* in_sizes, int n_in,
                              void* d_out, int out_size, void* d_ws, size_t ws_size,
                              hipStream_t stream)
{
  const int*   ids  = (const int*)  d_in[0];
  const float* emb  = (const float*)d_in[1];
  const float* lnw  = (const float*)d_in[2];
  const float* lnb  = (const float*)d_in[3];
  const float* ipw  = (const float*)d_in[4];
  const float* cw   = (const float*)d_in[5];
  const float* cb   = (const float*)d_in[6];
  const float* xpw  = (const float*)d_in[7];
  const float* dtw  = (const float*)d_in[8];
  const float* dtb  = (const float*)d_in[9];
  const float* alog = (const float*)d_in[10];
  const float* Dp   = (const float*)d_in[11];
  const float* opw  = (const float*)d_in[12];
  const float* mlnw = (const float*)d_in[13];
  const float* mlnb = (const float*)d_in[14];
  const float* w1   = (const float*)d_in[15];
  const float* b1   = (const float*)d_in[16];
  const float* w2   = (const float*)d_in[17];
  const float* b2   = (const float*)d_in[18];
  const float* flnw = (const float*)d_in[19];
  const float* flnb = (const float*)d_in[20];
  float* out = (float*)d_out;

  const size_t half = (size_t)Bn * Ln * DI * sizeof(unsigned short);  // 52,428,800 B
  unsigned short* xc = (unsigned short*)d_ws;                         // [B,L,DI] bf16
  unsigned short* zy = (unsigned short*)((char*)d_ws + half);         // z, then y in-place

  k1_embed_inproj<<<Bn * 5, 256, 0, stream>>>(ids, emb, lnw, lnb, ipw, xc, zy);
  k2_conv_scan<<<Bn, 256, 0, stream>>>(xc, zy, cw, cb, xpw, dtw, dtb, alog, Dp);
  k3_out_ffn<<<Bn, 512, 0, stream>>>(zy, opw, mlnw, mlnb, w1, b1, w2, b2,
                                     flnw, flnb, out);
}